// Round 10
// baseline (364.451 us; speedup 1.0000x reference)
//
#include <hip/hip_runtime.h>

#define S_LEN 2048
#define HID   2048
#define NHEAD 16
#define HDIM  128
#define BATCH 2
#define KDIM  2048

using bf16x8  = __attribute__((ext_vector_type(8))) short;
using f32x4   = __attribute__((ext_vector_type(4))) float;
using short4v = __attribute__((ext_vector_type(4))) short;

__device__ __forceinline__ short f2bf(float f) {
  union { float f; unsigned u; } v; v.f = f;
  unsigned r = v.u + 0x7fffu + ((v.u >> 16) & 1u);
  return (short)(r >> 16);
}
__device__ __forceinline__ float bf2f(short s) {
  union { unsigned u; float f; } v;
  v.u = ((unsigned)(unsigned short)s) << 16;
  return v.f;
}

// async global->LDS, 16B per lane. LDS dest must be wave-uniform base + lane*16.
__device__ __forceinline__ void gl_lds16(const void* g, void* l) {
  __builtin_amdgcn_global_load_lds(
      (const __attribute__((address_space(1))) void*)g,
      (__attribute__((address_space(3))) void*)l, 16, 0, 0);
}

// ---------------- convert: hs, wq, wk, wv, wo  f32 -> bf16 -------------------
__global__ __launch_bounds__(256)
void convert_all(const float* __restrict__ hs, const float* __restrict__ wq,
                 const float* __restrict__ wk, const float* __restrict__ wv,
                 const float* __restrict__ wo,
                 short* __restrict__ hsb, short* __restrict__ wqkv,
                 short* __restrict__ wob)
{
  int i = blockIdx.x * 256 + threadIdx.x;
  const float* src; short* dst; int j = i;
  if (j < 1048576)      { src = hs; dst = hsb; }
  else if (j < 1572864) { j -= 1048576; src = wq; dst = wqkv; }
  else if (j < 2097152) { j -= 1572864; src = wk; dst = wqkv + 4194304; }
  else if (j < 2621440) { j -= 2097152; src = wv; dst = wqkv + 8388608; }
  else                  { j -= 2621440; src = wo; dst = wob; }
  f32x4 a = ((const f32x4*)src)[2 * j];
  f32x4 b = ((const f32x4*)src)[2 * j + 1];
  bf16x8 o;
  o[0]=f2bf(a[0]); o[1]=f2bf(a[1]); o[2]=f2bf(a[2]); o[3]=f2bf(a[3]);
  o[4]=f2bf(b[0]); o[5]=f2bf(b[1]); o[6]=f2bf(b[2]); o[7]=f2bf(b[3]);
  ((bf16x8*)dst)[j] = o;
}

// ---------------- 256x256 QKV GEMM, ring-2 / 2 blocks-per-CU -----------------
// C = A @ B^T + bias, A=[4096][2048] bf16, B=[6144][2048] bf16 (Wq|Wk|Wv rows).
// 512 thr = 8 waves (2M x 4N); per-wave 128x64 out (acc 8x4 f32x4 frags).
// BK=32, DOUBLE-buffered LDS (2 x 256x32 x 2 ops = 64 KiB -> 2 blocks/CU,
// 16 waves/CU: cross-block TLP covers the counted-vmcnt waits).
// One s_waitcnt vmcnt(2) per K-tile (T+1 h0's 2 loads may stay in flight).
// NO forced lgkmcnt drains inside the body: compiler emits fine-grained
// lgkmcnt and interleaves ds_read with MFMA. sched_barrier(0) only guards
// the raw s_barriers against load motion.
// LDS swizzle: 16B-chunk c ^= (row>>1)&3 (2-way = free); linear gl_lds dest +
// inverse-swizzled GLOBAL source (same involution; proven round 9, 0 conflicts).
__global__ __launch_bounds__(512)
void gemm256_qkv(const short* __restrict__ A, const short* __restrict__ B,
                 const float* __restrict__ bq, const float* __restrict__ bkb,
                 const float* __restrict__ bv,
                 short* __restrict__ Qo, short* __restrict__ Ko,
                 short* __restrict__ Vo)
{
  __shared__ __align__(16) short LA[2 * 256 * 32];
  __shared__ __align__(16) short LB[2 * 256 * 32];
  const int tid  = threadIdx.x;
  const int lane = tid & 63, wave = tid >> 6;
  const int ln = lane & 15, g = lane >> 4;
  const int wm = wave >> 2, wn = wave & 3;
  const int m0 = blockIdx.x * 256, n0 = blockIdx.y * 256;

  // staging: thread t covers row (t>>2) of a 128-row half, 16B chunk (t&3).
  // physical chunk p stores logical chunk p ^ ((row>>1)&3); fetch that.
  const int srow   = tid >> 2;
  const int schunk = (tid & 3) ^ ((tid >> 3) & 3);
  const short* aSrc = A + (size_t)(m0 + srow) * KDIM + schunk * 8;
  const short* bSrc = B + (size_t)(n0 + srow) * KDIM + schunk * 8;

  // LDS read offsets; (row>>1)&3 invariant across 16-row frag steps.
  const int arow = wm * 128 + ln;
  const int aRd  = arow * 32 + ((g ^ ((arow >> 1) & 3)) << 3);
  const int brow = wn * 64 + ln;
  const int bRd  = brow * 32 + ((g ^ ((brow >> 1) & 3)) << 3);

  auto stage = [&](int t, int h) {
    gl_lds16(aSrc + (size_t)h * (128 * KDIM) + t * 32,
             &LA[((t & 1) * 8192) + h * 4096 + tid * 8]);
    gl_lds16(bSrc + (size_t)h * (128 * KDIM) + t * 32,
             &LB[((t & 1) * 8192) + h * 4096 + tid * 8]);
  };

  f32x4 acc[8][4] = {};

  // prologue: stage tile 0 fully (4 loads/thread in flight)
  stage(0, 0); stage(0, 1);

#define TILE_STEP(TT, VMC, DO_STAGE)                                           \
  {                                                                            \
    const int p_ = (TT) & 1;                                                   \
    if (DO_STAGE) { stage((TT) + 1, 0); }                                      \
    asm volatile("s_waitcnt vmcnt(" #VMC ")" ::: "memory");                    \
    __builtin_amdgcn_s_barrier();                                              \
    __builtin_amdgcn_sched_barrier(0);                                         \
    const short* la_ = &LA[p_ * 8192];                                         \
    const short* lb_ = &LB[p_ * 8192];                                         \
    bf16x8 af_[4], bf_[4];                                                     \
    _Pragma("unroll")                                                          \
    for (int mf = 0; mf < 4; ++mf)                                             \
      af_[mf] = *(const bf16x8*)(la_ + aRd + mf * 512);                        \
    _Pragma("unroll")                                                          \
    for (int nf = 0; nf < 4; ++nf)                                             \
      bf_[nf] = *(const bf16x8*)(lb_ + bRd + nf * 512);                        \
    _Pragma("unroll")                                                          \
    for (int mf = 0; mf < 4; ++mf)                                             \
      _Pragma("unroll")                                                        \
      for (int nf = 0; nf < 4; ++nf)                                           \
        acc[mf][nf] = __builtin_amdgcn_mfma_f32_16x16x32_bf16(                 \
            af_[mf], bf_[nf], acc[mf][nf], 0, 0, 0);                           \
    if (DO_STAGE) { stage((TT) + 1, 1); }                                      \
    _Pragma("unroll")                                                          \
    for (int mf = 0; mf < 4; ++mf)                                             \
      af_[mf] = *(const bf16x8*)(la_ + aRd + (4 + mf) * 512);                  \
    _Pragma("unroll")                                                          \
    for (int mf = 0; mf < 4; ++mf)                                             \
      _Pragma("unroll")                                                        \
      for (int nf = 0; nf < 4; ++nf)                                           \
        acc[4 + mf][nf] = __builtin_amdgcn_mfma_f32_16x16x32_bf16(             \
            af_[mf], bf_[nf], acc[4 + mf][nf], 0, 0, 0);                       \
    __builtin_amdgcn_sched_barrier(0);                                         \
    __builtin_amdgcn_s_barrier();                                              \
  }

  for (int T = 0; T < 63; ++T) TILE_STEP(T, 2, true);
  TILE_STEP(63, 0, false);
#undef TILE_STEP

  // epilogue: bias + scatter to Q/K ([b][h][s][d]) or V^T ([b][h][d][s])
  const int seg   = blockIdx.y >> 3;            // 0=Q 1=K 2=V
  const int nTile = n0 & 2047;
  const float* bias = (seg == 0) ? bq : (seg == 1) ? bkb : bv;
  float bvv[4];
#pragma unroll
  for (int nf = 0; nf < 4; ++nf) bvv[nf] = bias[nTile + wn * 64 + nf * 16 + ln];

  if (seg < 2) {
    short* C = seg ? Ko : Qo;
#pragma unroll
    for (int mf = 0; mf < 8; ++mf) {
      const int mb = m0 + wm * 128 + mf * 16 + 4 * g;
      const int bb = mb >> 11, t = mb & (S_LEN - 1);
#pragma unroll
      for (int nf = 0; nf < 4; ++nf) {
        const int nl = nTile + wn * 64 + nf * 16 + ln;
        const int h = nl >> 7, d = nl & 127;
#pragma unroll
        for (int e = 0; e < 4; ++e)
          C[((size_t)((bb * NHEAD + h) * S_LEN + t + e) << 7) + d] =
              f2bf(acc[mf][nf][e] + bvv[nf]);
      }
    }
  } else {
    short* C = Vo;
#pragma unroll
    for (int mf = 0; mf < 8; ++mf) {
      const int mb = m0 + wm * 128 + mf * 16 + 4 * g;
      const int bb = mb >> 11, t0 = mb & (S_LEN - 1);
#pragma unroll
      for (int nf = 0; nf < 4; ++nf) {
        const int nl = nTile + wn * 64 + nf * 16 + ln;
        const int h = nl >> 7, d = nl & 127;
        short4v v;
#pragma unroll
        for (int e = 0; e < 4; ++e) v[e] = f2bf(acc[mf][nf][e] + bvv[nf]);
        *(short4v*)&C[((size_t)((bb * NHEAD + h) * HDIM + d)) * S_LEN + t0] = v;
      }
    }
  }
}

// ---------------- bf16 GEMM, C = A @ B^T + bias (m97 structure) --------------
// retained for the O-projection (512 blocks fill the chip at 4 blocks/CU).
template<int KIND>
__global__ __launch_bounds__(256)
void gemm128(const short* __restrict__ A, const short* __restrict__ B,
             const float* __restrict__ bias0, const float* __restrict__ bias1,
             const float* __restrict__ bias2,
             void* __restrict__ O0, void* __restrict__ O1, void* __restrict__ O2)
{
  __shared__ __align__(16) short As[128 * 32];
  __shared__ __align__(16) short Bs[128 * 32];
  const int tid  = threadIdx.x;
  const int lane = tid & 63, wave = tid >> 6;
  const int ln = lane & 15, g = lane >> 4;
  const int wr = wave >> 1, wc = wave & 1;
  const int m0 = blockIdx.x * 128, n0 = blockIdx.y * 128;

  const int c0 = tid, c1 = tid + 256;
  const short* aP0 = A + (size_t)(m0 + (c0 >> 2)) * KDIM + (c0 & 3) * 8;
  const short* aP1 = A + (size_t)(m0 + (c1 >> 2)) * KDIM + (c1 & 3) * 8;
  const short* bP0 = B + (size_t)(n0 + (c0 >> 2)) * KDIM + (c0 & 3) * 8;
  const short* bP1 = B + (size_t)(n0 + (c1 >> 2)) * KDIM + (c1 & 3) * 8;

  f32x4 acc[4][4] = {};

  for (int k0 = 0; k0 < KDIM; k0 += 32) {
    __syncthreads();
    gl_lds16(aP0 + k0, &As[c0 * 8]);
    gl_lds16(aP1 + k0, &As[c1 * 8]);
    gl_lds16(bP0 + k0, &Bs[c0 * 8]);
    gl_lds16(bP1 + k0, &Bs[c1 * 8]);
    __syncthreads();

    bf16x8 af[4], bfm[4];
#pragma unroll
    for (int i = 0; i < 4; ++i)
      af[i] = *(const bf16x8*)&As[(wr * 64 + i * 16 + ln) * 32 + g * 8];
#pragma unroll
    for (int j = 0; j < 4; ++j)
      bfm[j] = *(const bf16x8*)&Bs[(wc * 64 + j * 16 + ln) * 32 + g * 8];
#pragma unroll
    for (int i = 0; i < 4; ++i)
#pragma unroll
      for (int j = 0; j < 4; ++j)
        acc[i][j] = __builtin_amdgcn_mfma_f32_16x16x32_bf16(af[i], bfm[j], acc[i][j], 0, 0, 0);
  }

  if constexpr (KIND == 0) {
    // unused this round
  } else {                   // O-proj -> f32
    float* C = (float*)O0;
    float bvv[4];
#pragma unroll
    for (int j = 0; j < 4; ++j) bvv[j] = bias0[n0 + wc * 64 + j * 16 + ln];
#pragma unroll
    for (int i = 0; i < 4; ++i) {
      const int mb = m0 + wr * 64 + i * 16 + 4 * g;
#pragma unroll
      for (int j = 0; j < 4; ++j) {
        const int n = n0 + wc * 64 + j * 16 + ln;
#pragma unroll
        for (int e = 0; e < 4; ++e)
          C[(size_t)(mb + e) * HID + n] = acc[i][j][e] + bvv[j];
      }
    }
  }
}

// ---------------- RoPE in-place on Q,K ([b][h][s][d] bf16) -------------------
// Q additionally pre-scaled by 1/sqrt(HD)*log2(e): softmax runs in exp2 domain.
#define QSCALE 0.12752767502f   // (1/sqrt(128)) * log2(e)
__global__ __launch_bounds__(256)
void rope_kernel(short* __restrict__ Qb, short* __restrict__ Kb,
                 const int* __restrict__ pos_ids)
{
  const int row = blockIdx.x * 4 + (threadIdx.x >> 6);
  const int d   = threadIdx.x & 63;
  const int bh  = row >> 11, t = row & (S_LEN - 1);
  const int b   = bh >> 4;
  const float pos = (float)pos_ids[b * S_LEN + t];
  const float inv = powf(10000.0f, -(float)d * (1.0f / 64.0f));
  float s, c;
  sincosf(pos * inv, &s, &c);
  const size_t base = (size_t)row * HDIM;
  {
    float x1 = bf2f(Qb[base + d]), x2 = bf2f(Qb[base + d + 64]);
    Qb[base + d]      = f2bf((x1 * c - x2 * s) * QSCALE);
    Qb[base + d + 64] = f2bf((x2 * c + x1 * s) * QSCALE);
  }
  {
    float x1 = bf2f(Kb[base + d]), x2 = bf2f(Kb[base + d + 64]);
    Kb[base + d]      = f2bf(x1 * c - x2 * s);
    Kb[base + d + 64] = f2bf(x2 * c + x1 * s);
  }
}

// ---------------- flash attention (round-8 structure, unchanged) -------------
__global__ __launch_bounds__(256)
void attn_kernel(const short* __restrict__ Qb, const short* __restrict__ Kb,
                 const short* __restrict__ Vt, short* __restrict__ AO)
{
  __shared__ __align__(16) short Ks[64 * 128];
  __shared__ __align__(16) short Vs[128 * 64];
  __shared__ __align__(16) short Ps[4][16 * 64];
  const int tid  = threadIdx.x;
  const int wave = tid >> 6, lane = tid & 63;
  const int ln = lane & 15, g = lane >> 4;
  const int bid = blockIdx.x;
  const int bh  = bid & 31;
  const int grp = bid >> 5;
  const int yt  = (grp & 1) ? (31 - (grp >> 1)) : (grp >> 1);
  const int qw  = yt * 64 + wave * 16;

  bf16x8 qf[4];
#pragma unroll
  for (int ks = 0; ks < 4; ++ks)
    qf[ks] = *(const bf16x8*)&Qb[((size_t)bh * S_LEN + qw + ln) * HDIM + ks * 32 + g * 8];

  f32x4 o[8] = {};
  float m_e[4], l_e[4];
#pragma unroll
  for (int e = 0; e < 4; ++e) { m_e[e] = -3.0e38f; l_e[e] = 0.f; }

  for (int kvt = 0; kvt <= yt; ++kvt) {
    const int kv0 = kvt * 64;
    __syncthreads();
#pragma unroll
    for (int p = 0; p < 4; ++p) {
      const int gi = tid + p * 256;
      {  // K tile [64][128], row-XOR-swizzled
        const int row = gi >> 4, c8 = gi & 15;
        bf16x8 v = *(const bf16x8*)&Kb[((size_t)bh * S_LEN + kv0 + row) * HDIM + c8 * 8];
        *(bf16x8*)&Ks[(row * 128 + c8 * 8) ^ ((row & 7) << 3)] = v;
      }
      {  // V tile as [d=128][kv=64]
        const int dr = gi >> 3, cg = gi & 7;
        bf16x8 v = *(const bf16x8*)&Vt[((size_t)bh * HDIM + dr) * S_LEN + kv0 + cg * 8];
        *(bf16x8*)&Vs[(dr * 64 + cg * 8) ^ ((dr & 7) << 3)] = v;
      }
    }
    __syncthreads();

    // S = Q K^T  (exp2 domain: Q carries scale*log2e)
    f32x4 sfr[4] = {};
#pragma unroll
    for (int ks = 0; ks < 4; ++ks) {
#pragma unroll
      for (int nt = 0; nt < 4; ++nt) {
        const int row = nt * 16 + ln;
        bf16x8 kf = *(const bf16x8*)&Ks[(row * 128 + ks * 32 + g * 8) ^ ((ln & 7) << 3)];
        sfr[nt] = __builtin_amdgcn_mfma_f32_16x16x32_bf16(qf[ks], kf, sfr[nt], 0, 0, 0);
      }
    }

    // causal mask + online softmax (exp2 domain)
#pragma unroll
    for (int e = 0; e < 4; ++e) {
      const int q = qw + 4 * g + e;
      float rmax = -3.0e38f;
#pragma unroll
      for (int nt = 0; nt < 4; ++nt) {
        float v = sfr[nt][e];
        if (kv0 + nt * 16 + ln > q) v = -3.0e38f;
        sfr[nt][e] = v;
        rmax = fmaxf(rmax, v);
      }
#pragma unroll
      for (int msk = 1; msk < 16; msk <<= 1)
        rmax = fmaxf(rmax, __shfl_xor(rmax, msk));
      const float mnew = fmaxf(m_e[e], rmax);
      const float corr = exp2f(m_e[e] - mnew);
      m_e[e] = mnew;
      float psum = 0.f;
#pragma unroll
      for (int nt = 0; nt < 4; ++nt) {
        const float pv = exp2f(sfr[nt][e] - mnew);
        sfr[nt][e] = pv;
        psum += pv;
      }
      l_e[e] = l_e[e] * corr + psum;   // lane-local; reduced at epilogue
#pragma unroll
      for (int nt2 = 0; nt2 < 8; ++nt2) o[nt2][e] *= corr;
    }

    // P -> per-wave LDS (C-layout -> A-layout), swizzled
    short* pw = &Ps[wave][0];
#pragma unroll
    for (int e = 0; e < 4; ++e) {
      const int r = 4 * g + e;
#pragma unroll
      for (int nt = 0; nt < 4; ++nt) {
        const int cc = nt * 16 + ln;
        pw[(r * 64 + cc) ^ ((r & 7) << 3)] = f2bf(sfr[nt][e]);
      }
    }
    __syncthreads();

    // O += P V
#pragma unroll
    for (int ks2 = 0; ks2 < 2; ++ks2) {
      bf16x8 pa = *(const bf16x8*)&pw[(ln * 64 + ks2 * 32 + g * 8) ^ ((ln & 7) << 3)];
#pragma unroll
      for (int nt2 = 0; nt2 < 8; ++nt2) {
        const int row = nt2 * 16 + ln;
        bf16x8 vb = *(const bf16x8*)&Vs[(row * 64 + ks2 * 32 + g * 8) ^ ((ln & 7) << 3)];
        o[nt2] = __builtin_amdgcn_mfma_f32_16x16x32_bf16(pa, vb, o[nt2], 0, 0, 0);
      }
    }
  }

  // epilogue: reduce l, normalize, write
  const int b = bh >> 4, h = bh & 15;
#pragma unroll
  for (int e = 0; e < 4; ++e) {
    float l = l_e[e];
#pragma unroll
    for (int msk = 1; msk < 16; msk <<= 1)
      l += __shfl_xor(l, msk);
    const float inv = 1.0f / l;
    const int q = qw + 4 * g + e;
    short* dst = &AO[((size_t)b * S_LEN + q) * HID + h * HDIM];
#pragma unroll
    for (int nt2 = 0; nt2 < 8; ++nt2)
      dst[nt2 * 16 + ln] = f2bf(o[nt2][e] * inv);
  }
}

extern "C" void kernel_launch(void* const* d_in, const int* in_sizes, int n_in,
                              void* d_out, int out_size, void* d_ws, size_t ws_size,
                              hipStream_t stream)
{
  const float* hs = (const float*)d_in[0];
  const float* wq = (const float*)d_in[1];
  const float* bq = (const float*)d_in[2];
  const float* wk = (const float*)d_in[3];
  const float* bk = (const float*)d_in[4];
  const float* wv = (const float*)d_in[5];
  const float* bv = (const float*)d_in[6];
  const float* wo = (const float*)d_in[7];
  const float* bo = (const float*)d_in[8];
  const int*  pos = (const int*)d_in[10];
  float* out = (float*)d_out;

  const size_t TSZ = (size_t)BATCH * NHEAD * S_LEN * HDIM;  // 8388608 elems
  short* Qb   = (short*)d_ws;
  short* Kb   = Qb + TSZ;
  short* Vt   = Kb + TSZ;
  short* hsb  = Vt + TSZ;        // hs bf16; reused as AO after QKV GEMM
  short* AO   = hsb;
  short* Wqkv = hsb + TSZ;
  short* wob  = Wqkv + 12582912;

  convert_all<<<12288, 256, 0, stream>>>(hs, wq, wk, wv, wo, hsb, Wqkv, wob);
  gemm256_qkv<<<dim3(16, 24), 512, 0, stream>>>(hsb, Wqkv, bq, bk, bv, Qb, Kb, Vt);
  rope_kernel<<<(BATCH * NHEAD * S_LEN) / 4, 256, 0, stream>>>(Qb, Kb, pos);
  attn_kernel<<<1024, 256, 0, stream>>>(Qb, Kb, Vt, AO);
  gemm128<1><<<dim3(32, 16), 256, 0, stream>>>(AO, wob, bo, nullptr, nullptr, out, nullptr, nullptr);
}

// Round 11
// 290.864 us; speedup vs baseline: 1.2530x; 1.2530x over previous
//
#include <hip/hip_runtime.h>

#define S_LEN 2048
#define HID   2048
#define NHEAD 16
#define HDIM  128
#define BATCH 2
#define KDIM  2048

using bf16x8  = __attribute__((ext_vector_type(8))) short;
using f32x4   = __attribute__((ext_vector_type(4))) float;
using short4v = __attribute__((ext_vector_type(4))) short;

__device__ __forceinline__ short f2bf(float f) {
  union { float f; unsigned u; } v; v.f = f;
  unsigned r = v.u + 0x7fffu + ((v.u >> 16) & 1u);
  return (short)(r >> 16);
}
__device__ __forceinline__ float bf2f(short s) {
  union { unsigned u; float f; } v;
  v.u = ((unsigned)(unsigned short)s) << 16;
  return v.f;
}

// async global->LDS, 16B per lane. LDS dest must be wave-uniform base + lane*16.
__device__ __forceinline__ void gl_lds16(const void* g, void* l) {
  __builtin_amdgcn_global_load_lds(
      (const __attribute__((address_space(1))) void*)g,
      (__attribute__((address_space(3))) void*)l, 16, 0, 0);
}

// ---------------- convert: hs, wq, wk, wv, wo  f32 -> bf16 -------------------
__global__ __launch_bounds__(256)
void convert_all(const float* __restrict__ hs, const float* __restrict__ wq,
                 const float* __restrict__ wk, const float* __restrict__ wv,
                 const float* __restrict__ wo,
                 short* __restrict__ hsb, short* __restrict__ wqkv,
                 short* __restrict__ wob)
{
  int i = blockIdx.x * 256 + threadIdx.x;
  const float* src; short* dst; int j = i;
  if (j < 1048576)      { src = hs; dst = hsb; }
  else if (j < 1572864) { j -= 1048576; src = wq; dst = wqkv; }
  else if (j < 2097152) { j -= 1572864; src = wk; dst = wqkv + 4194304; }
  else if (j < 2621440) { j -= 2097152; src = wv; dst = wqkv + 8388608; }
  else                  { j -= 2621440; src = wo; dst = wob; }
  f32x4 a = ((const f32x4*)src)[2 * j];
  f32x4 b = ((const f32x4*)src)[2 * j + 1];
  bf16x8 o;
  o[0]=f2bf(a[0]); o[1]=f2bf(a[1]); o[2]=f2bf(a[2]); o[3]=f2bf(a[3]);
  o[4]=f2bf(b[0]); o[5]=f2bf(b[1]); o[6]=f2bf(b[2]); o[7]=f2bf(b[3]);
  ((bf16x8*)dst)[j] = o;
}

// ---------------- bf16 GEMM, C = A @ B^T + bias ------------------------------
// gemm128 skeleton (proven 4 blocks/CU TLP) with BK=64: half the barrier
// drains per K-loop (the m97 structure's ~20% stall). [128][64] LDS would be a
// 16-way read conflict -> chunk-XOR involution (chunk ^= row&7): linear gl_lds
// dest + inverse-swizzled GLOBAL source + swizzled read (2-way max = free;
// same algebra as r9/r10's verified 0-conflict staging). 32 KiB LDS.
template<int KIND>
__global__ __launch_bounds__(256)
void gemm128(const short* __restrict__ A, const short* __restrict__ B,
             const float* __restrict__ bias0, const float* __restrict__ bias1,
             const float* __restrict__ bias2,
             void* __restrict__ O0, void* __restrict__ O1, void* __restrict__ O2)
{
  __shared__ __align__(16) short As[128 * 64];
  __shared__ __align__(16) short Bs[128 * 64];
  const int tid  = threadIdx.x;
  const int lane = tid & 63, wave = tid >> 6;
  const int ln = lane & 15, g = lane >> 4;
  const int wr = wave >> 1, wc = wave & 1;
  const int m0 = blockIdx.x * 128, n0 = blockIdx.y * 128;

  // staging: issue j covers rows j*32 + (tid>>3), physical 16B-chunk tid&7.
  // physical chunk p holds logical chunk p ^ (row&7)  (row&7 == (tid>>3)&7,
  // invariant across j since 32 = 0 mod 8) -> fetch that from global.
  const int srow   = tid >> 3;
  const int schunk = (tid & 7) ^ (srow & 7);
  const short* aS = A + (size_t)(m0 + srow) * KDIM + schunk * 8;
  const short* bS = B + (size_t)(n0 + srow) * KDIM + schunk * 8;

  f32x4 acc[4][4] = {};

  for (int k0 = 0; k0 < KDIM; k0 += 64) {
    __syncthreads();
#pragma unroll
    for (int j = 0; j < 4; ++j) {
      gl_lds16(aS + k0 + j * (32 * KDIM), &As[j * 2048 + tid * 8]);
      gl_lds16(bS + k0 + j * (32 * KDIM), &Bs[j * 2048 + tid * 8]);
    }
    __syncthreads();

#pragma unroll
    for (int ks = 0; ks < 2; ++ks) {
      bf16x8 af[4], bfm[4];
#pragma unroll
      for (int i = 0; i < 4; ++i) {
        const int r = wr * 64 + i * 16 + ln;
        af[i] = *(const bf16x8*)&As[r * 64 + (((ks * 4 + g) ^ (r & 7)) << 3)];
      }
#pragma unroll
      for (int j2 = 0; j2 < 4; ++j2) {
        const int r = wc * 64 + j2 * 16 + ln;
        bfm[j2] = *(const bf16x8*)&Bs[r * 64 + (((ks * 4 + g) ^ (r & 7)) << 3)];
      }
#pragma unroll
      for (int i = 0; i < 4; ++i)
#pragma unroll
        for (int j2 = 0; j2 < 4; ++j2)
          acc[i][j2] = __builtin_amdgcn_mfma_f32_16x16x32_bf16(af[i], bfm[j2], acc[i][j2], 0, 0, 0);
    }
  }

  if constexpr (KIND == 0) {
    const int seg   = n0 >> 11;
    const int nbase = (n0 & 2047) + wc * 64;
    const float* bias = (seg == 0) ? bias0 : (seg == 1) ? bias1 : bias2;
    float bvv[4];
#pragma unroll
    for (int j = 0; j < 4; ++j) bvv[j] = bias[nbase + j * 16 + ln];
    if (seg < 2) {           // Q,K -> [b][h][s][d] bf16
      short* C = (short*)(seg ? O1 : O0);
#pragma unroll
      for (int i = 0; i < 4; ++i) {
        const int mb = m0 + wr * 64 + i * 16 + 4 * g;
#pragma unroll
        for (int j = 0; j < 4; ++j) {
          const int nl = nbase + j * 16 + ln;
          const int h = nl >> 7, d = nl & 127;
#pragma unroll
          for (int e = 0; e < 4; ++e) {
            const int m = mb + e, bb = m >> 11, t = m & (S_LEN - 1);
            C[((size_t)((bb * NHEAD + h) * S_LEN + t) << 7) + d] = f2bf(acc[i][j][e] + bvv[j]);
          }
        }
      }
    } else {                 // V -> transposed [b][h][d][s] bf16
      short* C = (short*)O2;
#pragma unroll
      for (int i = 0; i < 4; ++i) {
        const int mb = m0 + wr * 64 + i * 16 + 4 * g;
        const int bb = mb >> 11, t0 = mb & (S_LEN - 1);
#pragma unroll
        for (int j = 0; j < 4; ++j) {
          const int nl = nbase + j * 16 + ln;
          const int h = nl >> 7, d = nl & 127;
          short4v v;
#pragma unroll
          for (int e = 0; e < 4; ++e) v[e] = f2bf(acc[i][j][e] + bvv[j]);
          *(short4v*)&C[((size_t)((bb * NHEAD + h) * HDIM + d)) * S_LEN + t0] = v;
        }
      }
    }
  } else {                   // O-proj -> f32
    float* C = (float*)O0;
    float bvv[4];
#pragma unroll
    for (int j = 0; j < 4; ++j) bvv[j] = bias0[n0 + wc * 64 + j * 16 + ln];
#pragma unroll
    for (int i = 0; i < 4; ++i) {
      const int mb = m0 + wr * 64 + i * 16 + 4 * g;
#pragma unroll
      for (int j = 0; j < 4; ++j) {
        const int n = n0 + wc * 64 + j * 16 + ln;
#pragma unroll
        for (int e = 0; e < 4; ++e)
          C[(size_t)(mb + e) * HID + n] = acc[i][j][e] + bvv[j];
      }
    }
  }
}

// ---------------- RoPE in-place on Q,K ([b][h][s][d] bf16) -------------------
// Q additionally pre-scaled by 1/sqrt(HD)*log2(e): softmax runs in exp2 domain.
#define QSCALE 0.12752767502f   // (1/sqrt(128)) * log2(e)
__global__ __launch_bounds__(256)
void rope_kernel(short* __restrict__ Qb, short* __restrict__ Kb,
                 const int* __restrict__ pos_ids)
{
  const int row = blockIdx.x * 4 + (threadIdx.x >> 6);
  const int d   = threadIdx.x & 63;
  const int bh  = row >> 11, t = row & (S_LEN - 1);
  const int b   = bh >> 4;
  const float pos = (float)pos_ids[b * S_LEN + t];
  const float inv = powf(10000.0f, -(float)d * (1.0f / 64.0f));
  float s, c;
  sincosf(pos * inv, &s, &c);
  const size_t base = (size_t)row * HDIM;
  {
    float x1 = bf2f(Qb[base + d]), x2 = bf2f(Qb[base + d + 64]);
    Qb[base + d]      = f2bf((x1 * c - x2 * s) * QSCALE);
    Qb[base + d + 64] = f2bf((x2 * c + x1 * s) * QSCALE);
  }
  {
    float x1 = bf2f(Kb[base + d]), x2 = bf2f(Kb[base + d + 64]);
    Kb[base + d]      = f2bf(x1 * c - x2 * s);
    Kb[base + d + 64] = f2bf(x2 * c + x1 * s);
  }
}

// ---------------- flash attention (round-8 structure, unchanged) -------------
__global__ __launch_bounds__(256)
void attn_kernel(const short* __restrict__ Qb, const short* __restrict__ Kb,
                 const short* __restrict__ Vt, short* __restrict__ AO)
{
  __shared__ __align__(16) short Ks[64 * 128];
  __shared__ __align__(16) short Vs[128 * 64];
  __shared__ __align__(16) short Ps[4][16 * 64];
  const int tid  = threadIdx.x;
  const int wave = tid >> 6, lane = tid & 63;
  const int ln = lane & 15, g = lane >> 4;
  const int bid = blockIdx.x;
  const int bh  = bid & 31;
  const int grp = bid >> 5;
  const int yt  = (grp & 1) ? (31 - (grp >> 1)) : (grp >> 1);
  const int qw  = yt * 64 + wave * 16;

  bf16x8 qf[4];
#pragma unroll
  for (int ks = 0; ks < 4; ++ks)
    qf[ks] = *(const bf16x8*)&Qb[((size_t)bh * S_LEN + qw + ln) * HDIM + ks * 32 + g * 8];

  f32x4 o[8] = {};
  float m_e[4], l_e[4];
#pragma unroll
  for (int e = 0; e < 4; ++e) { m_e[e] = -3.0e38f; l_e[e] = 0.f; }

  for (int kvt = 0; kvt <= yt; ++kvt) {
    const int kv0 = kvt * 64;
    __syncthreads();
#pragma unroll
    for (int p = 0; p < 4; ++p) {
      const int gi = tid + p * 256;
      {  // K tile [64][128], row-XOR-swizzled
        const int row = gi >> 4, c8 = gi & 15;
        bf16x8 v = *(const bf16x8*)&Kb[((size_t)bh * S_LEN + kv0 + row) * HDIM + c8 * 8];
        *(bf16x8*)&Ks[(row * 128 + c8 * 8) ^ ((row & 7) << 3)] = v;
      }
      {  // V tile as [d=128][kv=64]
        const int dr = gi >> 3, cg = gi & 7;
        bf16x8 v = *(const bf16x8*)&Vt[((size_t)bh * HDIM + dr) * S_LEN + kv0 + cg * 8];
        *(bf16x8*)&Vs[(dr * 64 + cg * 8) ^ ((dr & 7) << 3)] = v;
      }
    }
    __syncthreads();

    // S = Q K^T  (exp2 domain: Q carries scale*log2e)
    f32x4 sfr[4] = {};
#pragma unroll
    for (int ks = 0; ks < 4; ++ks) {
#pragma unroll
      for (int nt = 0; nt < 4; ++nt) {
        const int row = nt * 16 + ln;
        bf16x8 kf = *(const bf16x8*)&Ks[(row * 128 + ks * 32 + g * 8) ^ ((ln & 7) << 3)];
        sfr[nt] = __builtin_amdgcn_mfma_f32_16x16x32_bf16(qf[ks], kf, sfr[nt], 0, 0, 0);
      }
    }

    // causal mask + online softmax (exp2 domain)
#pragma unroll
    for (int e = 0; e < 4; ++e) {
      const int q = qw + 4 * g + e;
      float rmax = -3.0e38f;
#pragma unroll
      for (int nt = 0; nt < 4; ++nt) {
        float v = sfr[nt][e];
        if (kv0 + nt * 16 + ln > q) v = -3.0e38f;
        sfr[nt][e] = v;
        rmax = fmaxf(rmax, v);
      }
#pragma unroll
      for (int msk = 1; msk < 16; msk <<= 1)
        rmax = fmaxf(rmax, __shfl_xor(rmax, msk));
      const float mnew = fmaxf(m_e[e], rmax);
      const float corr = exp2f(m_e[e] - mnew);
      m_e[e] = mnew;
      float psum = 0.f;
#pragma unroll
      for (int nt = 0; nt < 4; ++nt) {
        const float pv = exp2f(sfr[nt][e] - mnew);
        sfr[nt][e] = pv;
        psum += pv;
      }
      l_e[e] = l_e[e] * corr + psum;   // lane-local; reduced at epilogue
#pragma unroll
      for (int nt2 = 0; nt2 < 8; ++nt2) o[nt2][e] *= corr;
    }

    // P -> per-wave LDS (C-layout -> A-layout), swizzled
    short* pw = &Ps[wave][0];
#pragma unroll
    for (int e = 0; e < 4; ++e) {
      const int r = 4 * g + e;
#pragma unroll
      for (int nt = 0; nt < 4; ++nt) {
        const int cc = nt * 16 + ln;
        pw[(r * 64 + cc) ^ ((r & 7) << 3)] = f2bf(sfr[nt][e]);
      }
    }
    __syncthreads();

    // O += P V
#pragma unroll
    for (int ks2 = 0; ks2 < 2; ++ks2) {
      bf16x8 pa = *(const bf16x8*)&pw[(ln * 64 + ks2 * 32 + g * 8) ^ ((ln & 7) << 3)];
#pragma unroll
      for (int nt2 = 0; nt2 < 8; ++nt2) {
        const int row = nt2 * 16 + ln;
        bf16x8 vb = *(const bf16x8*)&Vs[(row * 64 + ks2 * 32 + g * 8) ^ ((ln & 7) << 3)];
        o[nt2] = __builtin_amdgcn_mfma_f32_16x16x32_bf16(pa, vb, o[nt2], 0, 0, 0);
      }
    }
  }

  // epilogue: reduce l, normalize, write
  const int b = bh >> 4, h = bh & 15;
#pragma unroll
  for (int e = 0; e < 4; ++e) {
    float l = l_e[e];
#pragma unroll
    for (int msk = 1; msk < 16; msk <<= 1)
      l += __shfl_xor(l, msk);
    const float inv = 1.0f / l;
    const int q = qw + 4 * g + e;
    short* dst = &AO[((size_t)b * S_LEN + q) * HID + h * HDIM];
#pragma unroll
    for (int nt2 = 0; nt2 < 8; ++nt2)
      dst[nt2 * 16 + ln] = f2bf(o[nt2][e] * inv);
  }
}

extern "C" void kernel_launch(void* const* d_in, const int* in_sizes, int n_in,
                              void* d_out, int out_size, void* d_ws, size_t ws_size,
                              hipStream_t stream)
{
  const float* hs = (const float*)d_in[0];
  const float* wq = (const float*)d_in[1];
  const float* bq = (const float*)d_in[2];
  const float* wk = (const float*)d_in[3];
  const float* bk = (const float*)d_in[4];
  const float* wv = (const float*)d_in[5];
  const float* bv = (const float*)d_in[6];
  const float* wo = (const float*)d_in[7];
  const float* bo = (const float*)d_in[8];
  const int*  pos = (const int*)d_in[10];
  float* out = (float*)d_out;

  const size_t TSZ = (size_t)BATCH * NHEAD * S_LEN * HDIM;  // 8388608 elems
  short* Qb   = (short*)d_ws;
  short* Kb   = Qb + TSZ;
  short* Vt   = Kb + TSZ;
  short* hsb  = Vt + TSZ;        // hs bf16; reused as AO after QKV GEMM
  short* AO   = hsb;
  short* Wqkv = hsb + TSZ;
  short* wob  = Wqkv + 12582912;

  convert_all<<<12288, 256, 0, stream>>>(hs, wq, wk, wv, wo, hsb, Wqkv, wob);
  gemm128<0><<<dim3(32, 48), 256, 0, stream>>>(hsb, Wqkv, bq, bk, bv, Qb, Kb, Vt);
  rope_kernel<<<(BATCH * NHEAD * S_LEN) / 4, 256, 0, stream>>>(Qb, Kb, pos);
  attn_kernel<<<1024, 256, 0, stream>>>(Qb, Kb, Vt, AO);
  gemm128<1><<<dim3(32, 16), 256, 0, stream>>>(AO, wob, bo, nullptr, nullptr, out, nullptr, nullptr);
}

// Round 12
// 287.935 us; speedup vs baseline: 1.2657x; 1.0102x over previous
//
#include <hip/hip_runtime.h>

#define S_LEN 2048
#define HID   2048
#define NHEAD 16
#define HDIM  128
#define BATCH 2
#define KDIM  2048

using bf16x8  = __attribute__((ext_vector_type(8))) short;
using f32x4   = __attribute__((ext_vector_type(4))) float;
using short4v = __attribute__((ext_vector_type(4))) short;

__device__ __forceinline__ short f2bf(float f) {
  union { float f; unsigned u; } v; v.f = f;
  unsigned r = v.u + 0x7fffu + ((v.u >> 16) & 1u);
  return (short)(r >> 16);
}
__device__ __forceinline__ float bf2f(short s) {
  union { unsigned u; float f; } v;
  v.u = ((unsigned)(unsigned short)s) << 16;
  return v.f;
}

// async global->LDS, 16B per lane. LDS dest must be wave-uniform base + lane*16.
__device__ __forceinline__ void gl_lds16(const void* g, void* l) {
  __builtin_amdgcn_global_load_lds(
      (const __attribute__((address_space(1))) void*)g,
      (__attribute__((address_space(3))) void*)l, 16, 0, 0);
}

// ---------------- convert: hs, wq, wk, wv, wo  f32 -> bf16 -------------------
__global__ __launch_bounds__(256)
void convert_all(const float* __restrict__ hs, const float* __restrict__ wq,
                 const float* __restrict__ wk, const float* __restrict__ wv,
                 const float* __restrict__ wo,
                 short* __restrict__ hsb, short* __restrict__ wqkv,
                 short* __restrict__ wob)
{
  int i = blockIdx.x * 256 + threadIdx.x;
  const float* src; short* dst; int j = i;
  if (j < 1048576)      { src = hs; dst = hsb; }
  else if (j < 1572864) { j -= 1048576; src = wq; dst = wqkv; }
  else if (j < 2097152) { j -= 1572864; src = wk; dst = wqkv + 4194304; }
  else if (j < 2621440) { j -= 2097152; src = wv; dst = wqkv + 8388608; }
  else                  { j -= 2621440; src = wo; dst = wob; }
  f32x4 a = ((const f32x4*)src)[2 * j];
  f32x4 b = ((const f32x4*)src)[2 * j + 1];
  bf16x8 o;
  o[0]=f2bf(a[0]); o[1]=f2bf(a[1]); o[2]=f2bf(a[2]); o[3]=f2bf(a[3]);
  o[4]=f2bf(b[0]); o[5]=f2bf(b[1]); o[6]=f2bf(b[2]); o[7]=f2bf(b[3]);
  ((bf16x8*)dst)[j] = o;
}

// ---------------- bf16 GEMM, C = A @ B^T + bias (BK=64, swizzled; r11) -------
template<int KIND>
__global__ __launch_bounds__(256)
void gemm128(const short* __restrict__ A, const short* __restrict__ B,
             const float* __restrict__ bias0, const float* __restrict__ bias1,
             const float* __restrict__ bias2,
             void* __restrict__ O0, void* __restrict__ O1, void* __restrict__ O2)
{
  __shared__ __align__(16) short As[128 * 64];
  __shared__ __align__(16) short Bs[128 * 64];
  const int tid  = threadIdx.x;
  const int lane = tid & 63, wave = tid >> 6;
  const int ln = lane & 15, g = lane >> 4;
  const int wr = wave >> 1, wc = wave & 1;
  const int m0 = blockIdx.x * 128, n0 = blockIdx.y * 128;

  const int srow   = tid >> 3;
  const int schunk = (tid & 7) ^ (srow & 7);
  const short* aS = A + (size_t)(m0 + srow) * KDIM + schunk * 8;
  const short* bS = B + (size_t)(n0 + srow) * KDIM + schunk * 8;

  f32x4 acc[4][4] = {};

  for (int k0 = 0; k0 < KDIM; k0 += 64) {
    __syncthreads();
#pragma unroll
    for (int j = 0; j < 4; ++j) {
      gl_lds16(aS + k0 + j * (32 * KDIM), &As[j * 2048 + tid * 8]);
      gl_lds16(bS + k0 + j * (32 * KDIM), &Bs[j * 2048 + tid * 8]);
    }
    __syncthreads();

#pragma unroll
    for (int ks = 0; ks < 2; ++ks) {
      bf16x8 af[4], bfm[4];
#pragma unroll
      for (int i = 0; i < 4; ++i) {
        const int r = wr * 64 + i * 16 + ln;
        af[i] = *(const bf16x8*)&As[r * 64 + (((ks * 4 + g) ^ (r & 7)) << 3)];
      }
#pragma unroll
      for (int j2 = 0; j2 < 4; ++j2) {
        const int r = wc * 64 + j2 * 16 + ln;
        bfm[j2] = *(const bf16x8*)&Bs[r * 64 + (((ks * 4 + g) ^ (r & 7)) << 3)];
      }
#pragma unroll
      for (int i = 0; i < 4; ++i)
#pragma unroll
        for (int j2 = 0; j2 < 4; ++j2)
          acc[i][j2] = __builtin_amdgcn_mfma_f32_16x16x32_bf16(af[i], bfm[j2], acc[i][j2], 0, 0, 0);
    }
  }

  if constexpr (KIND == 0) {
    const int seg   = n0 >> 11;
    const int nbase = (n0 & 2047) + wc * 64;
    const float* bias = (seg == 0) ? bias0 : (seg == 1) ? bias1 : bias2;
    float bvv[4];
#pragma unroll
    for (int j = 0; j < 4; ++j) bvv[j] = bias[nbase + j * 16 + ln];
    if (seg < 2) {           // Q,K -> [b][h][s][d] bf16
      short* C = (short*)(seg ? O1 : O0);
#pragma unroll
      for (int i = 0; i < 4; ++i) {
        const int mb = m0 + wr * 64 + i * 16 + 4 * g;
#pragma unroll
        for (int j = 0; j < 4; ++j) {
          const int nl = nbase + j * 16 + ln;
          const int h = nl >> 7, d = nl & 127;
#pragma unroll
          for (int e = 0; e < 4; ++e) {
            const int m = mb + e, bb = m >> 11, t = m & (S_LEN - 1);
            C[((size_t)((bb * NHEAD + h) * S_LEN + t) << 7) + d] = f2bf(acc[i][j][e] + bvv[j]);
          }
        }
      }
    } else {                 // V -> transposed [b][h][d][s] bf16
      short* C = (short*)O2;
#pragma unroll
      for (int i = 0; i < 4; ++i) {
        const int mb = m0 + wr * 64 + i * 16 + 4 * g;
        const int bb = mb >> 11, t0 = mb & (S_LEN - 1);
#pragma unroll
        for (int j = 0; j < 4; ++j) {
          const int nl = nbase + j * 16 + ln;
          const int h = nl >> 7, d = nl & 127;
          short4v v;
#pragma unroll
          for (int e = 0; e < 4; ++e) v[e] = f2bf(acc[i][j][e] + bvv[j]);
          *(short4v*)&C[((size_t)((bb * NHEAD + h) * HDIM + d)) * S_LEN + t0] = v;
        }
      }
    }
  } else {                   // O-proj -> f32
    float* C = (float*)O0;
    float bvv[4];
#pragma unroll
    for (int j = 0; j < 4; ++j) bvv[j] = bias0[n0 + wc * 64 + j * 16 + ln];
#pragma unroll
    for (int i = 0; i < 4; ++i) {
      const int mb = m0 + wr * 64 + i * 16 + 4 * g;
#pragma unroll
      for (int j = 0; j < 4; ++j) {
        const int n = n0 + wc * 64 + j * 16 + ln;
#pragma unroll
        for (int e = 0; e < 4; ++e)
          C[(size_t)(mb + e) * HID + n] = acc[i][j][e] + bvv[j];
      }
    }
  }
}

// ---------------- RoPE in-place on Q,K ([b][h][s][d] bf16) -------------------
// Q additionally pre-scaled by 1/sqrt(HD)*log2(e): softmax runs in exp2 domain.
#define QSCALE 0.12752767502f   // (1/sqrt(128)) * log2(e)
__global__ __launch_bounds__(256)
void rope_kernel(short* __restrict__ Qb, short* __restrict__ Kb,
                 const int* __restrict__ pos_ids)
{
  const int row = blockIdx.x * 4 + (threadIdx.x >> 6);
  const int d   = threadIdx.x & 63;
  const int bh  = row >> 11, t = row & (S_LEN - 1);
  const int b   = bh >> 4;
  const float pos = (float)pos_ids[b * S_LEN + t];
  const float inv = powf(10000.0f, -(float)d * (1.0f / 64.0f));
  float s, c;
  sincosf(pos * inv, &s, &c);
  const size_t base = (size_t)row * HDIM;
  {
    float x1 = bf2f(Qb[base + d]), x2 = bf2f(Qb[base + d + 64]);
    Qb[base + d]      = f2bf((x1 * c - x2 * s) * QSCALE);
    Qb[base + d + 64] = f2bf((x2 * c + x1 * s) * QSCALE);
  }
  {
    float x1 = bf2f(Kb[base + d]), x2 = bf2f(Kb[base + d + 64]);
    Kb[base + d]      = f2bf(x1 * c - x2 * s);
    Kb[base + d + 64] = f2bf(x2 * c + x1 * s);
  }
}

// ---------------- flash attention ------------------------------------------
// Round-8 structure + ONE new mechanism: wave-uniform defer-rescale (T13,
// THR=8 in exp2 domain). __any makes the branch wave-uniform (scalar
// s_cbranch, no exec divergence) -- unlike r6's per-row divergent version.
// On most tiles the running max doesn't grow >8, skipping the 128 v_mul
// O-rescale + 4 exp2. First tile always takes the rescale path (m=-3e38).
__global__ __launch_bounds__(256)
void attn_kernel(const short* __restrict__ Qb, const short* __restrict__ Kb,
                 const short* __restrict__ Vt, short* __restrict__ AO)
{
  __shared__ __align__(16) short Ks[64 * 128];
  __shared__ __align__(16) short Vs[128 * 64];
  __shared__ __align__(16) short Ps[4][16 * 64];
  const int tid  = threadIdx.x;
  const int wave = tid >> 6, lane = tid & 63;
  const int ln = lane & 15, g = lane >> 4;
  const int bid = blockIdx.x;
  const int bh  = bid & 31;
  const int grp = bid >> 5;
  const int yt  = (grp & 1) ? (31 - (grp >> 1)) : (grp >> 1);
  const int qw  = yt * 64 + wave * 16;

  bf16x8 qf[4];
#pragma unroll
  for (int ks = 0; ks < 4; ++ks)
    qf[ks] = *(const bf16x8*)&Qb[((size_t)bh * S_LEN + qw + ln) * HDIM + ks * 32 + g * 8];

  f32x4 o[8] = {};
  float m_e[4], l_e[4];
#pragma unroll
  for (int e = 0; e < 4; ++e) { m_e[e] = -3.0e38f; l_e[e] = 0.f; }

  for (int kvt = 0; kvt <= yt; ++kvt) {
    const int kv0 = kvt * 64;
    __syncthreads();
#pragma unroll
    for (int p = 0; p < 4; ++p) {
      const int gi = tid + p * 256;
      {  // K tile [64][128], row-XOR-swizzled
        const int row = gi >> 4, c8 = gi & 15;
        bf16x8 v = *(const bf16x8*)&Kb[((size_t)bh * S_LEN + kv0 + row) * HDIM + c8 * 8];
        *(bf16x8*)&Ks[(row * 128 + c8 * 8) ^ ((row & 7) << 3)] = v;
      }
      {  // V tile as [d=128][kv=64]
        const int dr = gi >> 3, cg = gi & 7;
        bf16x8 v = *(const bf16x8*)&Vt[((size_t)bh * HDIM + dr) * S_LEN + kv0 + cg * 8];
        *(bf16x8*)&Vs[(dr * 64 + cg * 8) ^ ((dr & 7) << 3)] = v;
      }
    }
    __syncthreads();

    // S = Q K^T  (exp2 domain: Q carries scale*log2e)
    f32x4 sfr[4] = {};
#pragma unroll
    for (int ks = 0; ks < 4; ++ks) {
#pragma unroll
      for (int nt = 0; nt < 4; ++nt) {
        const int row = nt * 16 + ln;
        bf16x8 kf = *(const bf16x8*)&Ks[(row * 128 + ks * 32 + g * 8) ^ ((ln & 7) << 3)];
        sfr[nt] = __builtin_amdgcn_mfma_f32_16x16x32_bf16(qf[ks], kf, sfr[nt], 0, 0, 0);
      }
    }

    // causal mask + row-max
    float rmax_e[4];
#pragma unroll
    for (int e = 0; e < 4; ++e) {
      const int q = qw + 4 * g + e;
      float rmax = -3.0e38f;
#pragma unroll
      for (int nt = 0; nt < 4; ++nt) {
        float v = sfr[nt][e];
        if (kv0 + nt * 16 + ln > q) v = -3.0e38f;
        sfr[nt][e] = v;
        rmax = fmaxf(rmax, v);
      }
#pragma unroll
      for (int msk = 1; msk < 16; msk <<= 1)
        rmax = fmaxf(rmax, __shfl_xor(rmax, msk));
      rmax_e[e] = rmax;
    }

    // wave-uniform defer-rescale: only pay corr+o-rescale when max grew >8.
    bool grow = false;
#pragma unroll
    for (int e = 0; e < 4; ++e) grow |= (rmax_e[e] > m_e[e] + 8.0f);
    if (__any(grow)) {
#pragma unroll
      for (int e = 0; e < 4; ++e) {
        const float nm = fmaxf(m_e[e], rmax_e[e]);
        const float corr = exp2f(m_e[e] - nm);
        m_e[e] = nm;
        l_e[e] *= corr;
#pragma unroll
        for (int nt2 = 0; nt2 < 8; ++nt2) o[nt2][e] *= corr;
      }
    }

    // P = exp2(S - m) (bounded by 2^8 when deferred); lane-local l partials
#pragma unroll
    for (int e = 0; e < 4; ++e) {
      float psum = 0.f;
#pragma unroll
      for (int nt = 0; nt < 4; ++nt) {
        const float pv = exp2f(sfr[nt][e] - m_e[e]);
        sfr[nt][e] = pv;
        psum += pv;
      }
      l_e[e] += psum;
    }

    // P -> per-wave LDS (C-layout -> A-layout), swizzled
    short* pw = &Ps[wave][0];
#pragma unroll
    for (int e = 0; e < 4; ++e) {
      const int r = 4 * g + e;
#pragma unroll
      for (int nt = 0; nt < 4; ++nt) {
        const int cc = nt * 16 + ln;
        pw[(r * 64 + cc) ^ ((r & 7) << 3)] = f2bf(sfr[nt][e]);
      }
    }
    __syncthreads();

    // O += P V
#pragma unroll
    for (int ks2 = 0; ks2 < 2; ++ks2) {
      bf16x8 pa = *(const bf16x8*)&pw[(ln * 64 + ks2 * 32 + g * 8) ^ ((ln & 7) << 3)];
#pragma unroll
      for (int nt2 = 0; nt2 < 8; ++nt2) {
        const int row = nt2 * 16 + ln;
        bf16x8 vb = *(const bf16x8*)&Vs[(row * 64 + ks2 * 32 + g * 8) ^ ((ln & 7) << 3)];
        o[nt2] = __builtin_amdgcn_mfma_f32_16x16x32_bf16(pa, vb, o[nt2], 0, 0, 0);
      }
    }
  }

  // epilogue: reduce l, normalize, write
  const int b = bh >> 4, h = bh & 15;
#pragma unroll
  for (int e = 0; e < 4; ++e) {
    float l = l_e[e];
#pragma unroll
    for (int msk = 1; msk < 16; msk <<= 1)
      l += __shfl_xor(l, msk);
    const float inv = 1.0f / l;
    const int q = qw + 4 * g + e;
    short* dst = &AO[((size_t)b * S_LEN + q) * HID + h * HDIM];
#pragma unroll
    for (int nt2 = 0; nt2 < 8; ++nt2)
      dst[nt2 * 16 + ln] = f2bf(o[nt2][e] * inv);
  }
}

extern "C" void kernel_launch(void* const* d_in, const int* in_sizes, int n_in,
                              void* d_out, int out_size, void* d_ws, size_t ws_size,
                              hipStream_t stream)
{
  const float* hs = (const float*)d_in[0];
  const float* wq = (const float*)d_in[1];
  const float* bq = (const float*)d_in[2];
  const float* wk = (const float*)d_in[3];
  const float* bk = (const float*)d_in[4];
  const float* wv = (const float*)d_in[5];
  const float* bv = (const float*)d_in[6];
  const float* wo = (const float*)d_in[7];
  const float* bo = (const float*)d_in[8];
  const int*  pos = (const int*)d_in[10];
  float* out = (float*)d_out;

  const size_t TSZ = (size_t)BATCH * NHEAD * S_LEN * HDIM;  // 8388608 elems
  short* Qb   = (short*)d_ws;
  short* Kb   = Qb + TSZ;
  short* Vt   = Kb + TSZ;
  short* hsb  = Vt + TSZ;        // hs bf16; reused as AO after QKV GEMM
  short* AO   = hsb;
  short* Wqkv = hsb + TSZ;
  short* wob  = Wqkv + 12582912;

  convert_all<<<12288, 256, 0, stream>>>(hs, wq, wk, wv, wo, hsb, Wqkv, wob);
  gemm128<0><<<dim3(32, 48), 256, 0, stream>>>(hsb, Wqkv, bq, bk, bv, Qb, Kb, Vt);
  rope_kernel<<<(BATCH * NHEAD * S_LEN) / 4, 256, 0, stream>>>(Qb, Kb, pos);
  attn_kernel<<<1024, 256, 0, stream>>>(Qb, Kb, Vt, AO);
  gemm128<1><<<dim3(32, 16), 256, 0, stream>>>(AO, wob, bo, nullptr, nullptr, out, nullptr, nullptr);
}